// Round 1
// baseline (747.467 us; speedup 1.0000x reference)
//
#include <hip/hip_runtime.h>

#define IN_DIM 128
#define HID 256
#define OUTD 64

// ---------------- degree / norm ----------------
__global__ void k_degrees(const int* __restrict__ src, const int* __restrict__ dst,
                          int* __restrict__ cs, int* __restrict__ cd, int E) {
    int e = blockIdx.x * blockDim.x + threadIdx.x;
    if (e < E) {
        atomicAdd(&cs[src[e]], 1);
        atomicAdd(&cd[dst[e]], 1);
    }
}

__global__ void k_norms(const int* __restrict__ cs, const int* __restrict__ cd,
                        float* __restrict__ ns, float* __restrict__ nd, int N) {
    int i = blockIdx.x * blockDim.x + threadIdx.x;
    if (i < N) {
        ns[i] = rsqrtf((float)max(cs[i], 1));
        nd[i] = rsqrtf((float)max(cd[i], 1));
    }
}

// ---------------- scan (exclusive prefix over cnt_dst -> eoff) ----------------
__global__ __launch_bounds__(1024) void k_scanA(const int* __restrict__ cnt,
                                                int* __restrict__ eoff,
                                                int* __restrict__ bsum, int N) {
    __shared__ int s[1024];
    int tid = threadIdx.x;
    int i = blockIdx.x * 1024 + tid;
    int v = (i < N) ? cnt[i] : 0;
    s[tid] = v;
    __syncthreads();
    for (int o = 1; o < 1024; o <<= 1) {
        int t = (tid >= o) ? s[tid - o] : 0;
        __syncthreads();
        s[tid] += t;
        __syncthreads();
    }
    if (i < N) eoff[i] = s[tid] - v;           // exclusive
    if (tid == 1023) bsum[blockIdx.x] = s[tid]; // block total
}

__global__ __launch_bounds__(1024) void k_scanB(int* __restrict__ bsum, int nb,
                                                int* __restrict__ eoff, int N, int E) {
    __shared__ int s[1024];
    int tid = threadIdx.x;
    int v = (tid < nb) ? bsum[tid] : 0;
    s[tid] = v;
    __syncthreads();
    for (int o = 1; o < 1024; o <<= 1) {
        int t = (tid >= o) ? s[tid - o] : 0;
        __syncthreads();
        s[tid] += t;
        __syncthreads();
    }
    if (tid < nb) bsum[tid] = s[tid] - v;      // exclusive block offsets
    if (tid == 0) eoff[N] = E;
}

__global__ void k_scanC(int* __restrict__ eoff, const int* __restrict__ bsum, int N) {
    int i = blockIdx.x * blockDim.x + threadIdx.x;
    if (i < N) eoff[i] += bsum[i >> 10];
}

// ---------------- CSR fill ----------------
__global__ void k_fill(const int* __restrict__ src, const int* __restrict__ dst,
                       const int* __restrict__ eoff, int* __restrict__ cursor,
                       int* __restrict__ esrc, int E) {
    int e = blockIdx.x * blockDim.x + threadIdx.x;
    if (e < E) {
        int d = dst[e];
        int pos = eoff[d] + atomicAdd(&cursor[d], 1);
        esrc[pos] = src[e];
    }
}

// ---------------- SPMM1: xagg[v] = ndst[v] * sum_{e: dst=v} h[src_e]*nsrc[src_e] ----------------
__global__ __launch_bounds__(128) void k_spmm1(const float* __restrict__ h,
                                               const int* __restrict__ eoff,
                                               const int* __restrict__ esrc,
                                               const float* __restrict__ ns,
                                               const float* __restrict__ nd,
                                               float* __restrict__ xagg) {
    int v = blockIdx.x;
    int d = threadIdx.x;  // 0..127
    int s0 = eoff[v], s1 = eoff[v + 1];
    float acc = 0.f;
    for (int i = s0; i < s1; ++i) {
        int s = esrc[i];
        acc += h[(size_t)s * IN_DIM + d] * ns[s];
    }
    xagg[(size_t)v * IN_DIM + d] = acc * nd[v];
}

// ---------------- tiled fp32 GEMM, C = A(MxK) * B(KxN), fused epilogues ----------------
// EPI==1 : C = relu(AB + bias) * clamp(p,0,1)   (bias,p are length-N vectors)
// EPI==2 : C = (AB) * rowscale[row]
template <int EPI>
__global__ __launch_bounds__(256) void k_gemm(const float* __restrict__ A,
                                              const float* __restrict__ B,
                                              const float* __restrict__ bias,
                                              const float* __restrict__ p,
                                              const float* __restrict__ rowscale,
                                              float* __restrict__ C,
                                              int M, int N, int K) {
    const int TBM = 64, TBN = 64, TBK = 16;
    __shared__ float As[TBK][TBM + 4];  // +4 pad: 16B-aligned rows, spread banks
    __shared__ float Bs[TBK][TBN];

    int t = threadIdx.x;
    int tx = t & 15, ty = t >> 4;
    int row0 = blockIdx.x * TBM, col0 = blockIdx.y * TBN;

    // A tile load mapping: thread -> (m, k4)
    int am = t >> 2;          // 0..63
    int ak = (t & 3) * 4;     // 0,4,8,12
    // B tile load mapping
    int bk = t >> 4;          // 0..15
    int bn = (t & 15) * 4;    // 0..60

    float acc[4][4] = {};

    for (int k0 = 0; k0 < K; k0 += TBK) {
        int arow = row0 + am;
        float4 av = make_float4(0.f, 0.f, 0.f, 0.f);
        if (arow < M) av = *(const float4*)(A + (size_t)arow * K + k0 + ak);
        As[ak + 0][am] = av.x;
        As[ak + 1][am] = av.y;
        As[ak + 2][am] = av.z;
        As[ak + 3][am] = av.w;

        float4 bv = *(const float4*)(B + (size_t)(k0 + bk) * N + col0 + bn);
        *(float4*)&Bs[bk][bn] = bv;
        __syncthreads();

#pragma unroll
        for (int k = 0; k < TBK; ++k) {
            float4 a4 = *(const float4*)&As[k][ty * 4];
            float4 b4 = *(const float4*)&Bs[k][tx * 4];
            float ar[4] = {a4.x, a4.y, a4.z, a4.w};
            float br[4] = {b4.x, b4.y, b4.z, b4.w};
#pragma unroll
            for (int i = 0; i < 4; ++i)
#pragma unroll
                for (int j = 0; j < 4; ++j) acc[i][j] += ar[i] * br[j];
        }
        __syncthreads();
    }

    int col = col0 + tx * 4;
    float4 b4 = make_float4(0.f, 0.f, 0.f, 0.f);
    float4 p4 = make_float4(1.f, 1.f, 1.f, 1.f);
    if (EPI == 1) {
        b4 = *(const float4*)(bias + col);
        float4 pr = *(const float4*)(p + col);
        p4.x = fminf(fmaxf(pr.x, 0.f), 1.f);
        p4.y = fminf(fmaxf(pr.y, 0.f), 1.f);
        p4.z = fminf(fmaxf(pr.z, 0.f), 1.f);
        p4.w = fminf(fmaxf(pr.w, 0.f), 1.f);
    }
#pragma unroll
    for (int i = 0; i < 4; ++i) {
        int row = row0 + ty * 4 + i;
        if (row < M) {
            float4 v = make_float4(acc[i][0], acc[i][1], acc[i][2], acc[i][3]);
            if (EPI == 1) {
                v.x = fmaxf(v.x + b4.x, 0.f) * p4.x;
                v.y = fmaxf(v.y + b4.y, 0.f) * p4.y;
                v.z = fmaxf(v.z + b4.z, 0.f) * p4.z;
                v.w = fmaxf(v.w + b4.w, 0.f) * p4.w;
            } else {
                float rs = rowscale[row];
                v.x *= rs; v.y *= rs; v.z *= rs; v.w *= rs;
            }
            *(float4*)(C + (size_t)row * N + col) = v;
        }
    }
}

// ---------------- SPMM2: out[v] = ndst[v] * sum_{e: dst=v} ysc[src_e] + b2 ----------------
__global__ __launch_bounds__(64) void k_spmm2(const float* __restrict__ ysc,
                                              const int* __restrict__ eoff,
                                              const int* __restrict__ esrc,
                                              const float* __restrict__ nd,
                                              const float* __restrict__ b2,
                                              float* __restrict__ out) {
    int v = blockIdx.x;
    int d = threadIdx.x;  // 0..63
    int s0 = eoff[v], s1 = eoff[v + 1];
    float acc = 0.f;
    for (int i = s0; i < s1; ++i) {
        acc += ysc[(size_t)esrc[i] * OUTD + d];
    }
    out[(size_t)v * OUTD + d] = acc * nd[v] + b2[d];
}

extern "C" void kernel_launch(void* const* d_in, const int* in_sizes, int n_in,
                              void* d_out, int out_size, void* d_ws, size_t ws_size,
                              hipStream_t stream) {
    const float* h  = (const float*)d_in[0];
    const float* W1 = (const float*)d_in[1];
    const float* b1 = (const float*)d_in[2];
    const float* W2 = (const float*)d_in[3];
    const float* b2 = (const float*)d_in[4];
    const float* p  = (const float*)d_in[5];
    const int* src  = (const int*)d_in[6];
    const int* dst  = (const int*)d_in[7];

    const int N = in_sizes[0] / IN_DIM;
    const int E = in_sizes[6];
    float* out = (float*)d_out;

    // workspace carve-up (256B aligned)
    char* ws = (char*)d_ws;
    size_t off = 0;
    auto alloc = [&](size_t bytes) -> void* {
        void* ptr = ws + off;
        off = (off + bytes + 255) & ~(size_t)255;
        return ptr;
    };
    int* cnt_src = (int*)alloc((size_t)N * 4);
    int* cnt_dst = (int*)alloc((size_t)N * 4);
    int* cursor  = (int*)alloc((size_t)N * 4);
    size_t zero_span = off;  // zero the first three regions in one memset
    int* eoff   = (int*)alloc((size_t)(N + 1) * 4);
    int* bsum   = (int*)alloc(4096);
    int* esrc   = (int*)alloc((size_t)E * 4);
    float* ns   = (float*)alloc((size_t)N * 4);
    float* nd   = (float*)alloc((size_t)N * 4);
    float* xagg = (float*)alloc((size_t)N * IN_DIM * 4);
    float* hid  = (float*)alloc((size_t)N * HID * 4);
    float* ysc  = xagg;  // reuse: xagg dead after GEMM1, ysc (N*64) fits in xagg (N*128)

    hipMemsetAsync(d_ws, 0, zero_span, stream);

    int tpb = 256;
    k_degrees<<<(E + tpb - 1) / tpb, tpb, 0, stream>>>(src, dst, cnt_src, cnt_dst, E);
    k_norms<<<(N + tpb - 1) / tpb, tpb, 0, stream>>>(cnt_src, cnt_dst, ns, nd, N);

    int nb = (N + 1023) / 1024;
    k_scanA<<<nb, 1024, 0, stream>>>(cnt_dst, eoff, bsum, N);
    k_scanB<<<1, 1024, 0, stream>>>(bsum, nb, eoff, N, E);
    k_scanC<<<(N + tpb - 1) / tpb, tpb, 0, stream>>>(eoff, bsum, N);
    k_fill<<<(E + tpb - 1) / tpb, tpb, 0, stream>>>(src, dst, eoff, cursor, esrc, E);

    k_spmm1<<<N, IN_DIM, 0, stream>>>(h, eoff, esrc, ns, nd, xagg);

    dim3 g1((N + 63) / 64, HID / 64);
    k_gemm<1><<<g1, 256, 0, stream>>>(xagg, W1, b1, p, nullptr, hid, N, HID, IN_DIM);

    dim3 g2((N + 63) / 64, OUTD / 64);
    k_gemm<2><<<g2, 256, 0, stream>>>(hid, W2, nullptr, nullptr, ns, ysc, N, OUTD, HID);

    k_spmm2<<<N, OUTD, 0, stream>>>(ysc, eoff, esrc, nd, b2, out);
}

// Round 2
// 607.058 us; speedup vs baseline: 1.2313x; 1.2313x over previous
//
#include <hip/hip_runtime.h>

#define IN_DIM 128
#define HID 256
#define OUTD 64

typedef __attribute__((ext_vector_type(8))) short bf16x8;
typedef __attribute__((ext_vector_type(4))) float f32x4;

// ---- bf16 helpers (RNE) ----
__device__ __forceinline__ unsigned short f2bf(float x) {
    unsigned int u = __float_as_uint(x);
    unsigned int r = (u + 0x7fffu + ((u >> 16) & 1u)) >> 16;
    return (unsigned short)r;
}
__device__ __forceinline__ float bf2f(unsigned short b) {
    return __uint_as_float(((unsigned int)b) << 16);
}

// ---------------- degree / norm ----------------
__global__ void k_degrees(const int* __restrict__ src, const int* __restrict__ dst,
                          int* __restrict__ cs, int* __restrict__ cd, int E) {
    int e = blockIdx.x * blockDim.x + threadIdx.x;
    if (e < E) {
        atomicAdd(&cs[src[e]], 1);
        atomicAdd(&cd[dst[e]], 1);
    }
}

__global__ void k_norms(const int* __restrict__ cs, const int* __restrict__ cd,
                        float* __restrict__ ns, float* __restrict__ nd, int N) {
    int i = blockIdx.x * blockDim.x + threadIdx.x;
    if (i < N) {
        ns[i] = rsqrtf((float)max(cs[i], 1));
        nd[i] = rsqrtf((float)max(cd[i], 1));
    }
}

// ---------------- scan ----------------
__global__ __launch_bounds__(1024) void k_scanA(const int* __restrict__ cnt,
                                                int* __restrict__ eoff,
                                                int* __restrict__ bsum, int N) {
    __shared__ int s[1024];
    int tid = threadIdx.x;
    int i = blockIdx.x * 1024 + tid;
    int v = (i < N) ? cnt[i] : 0;
    s[tid] = v;
    __syncthreads();
    for (int o = 1; o < 1024; o <<= 1) {
        int t = (tid >= o) ? s[tid - o] : 0;
        __syncthreads();
        s[tid] += t;
        __syncthreads();
    }
    if (i < N) eoff[i] = s[tid] - v;
    if (tid == 1023) bsum[blockIdx.x] = s[tid];
}

__global__ __launch_bounds__(1024) void k_scanB(int* __restrict__ bsum, int nb,
                                                int* __restrict__ eoff, int N, int E) {
    __shared__ int s[1024];
    int tid = threadIdx.x;
    int v = (tid < nb) ? bsum[tid] : 0;
    s[tid] = v;
    __syncthreads();
    for (int o = 1; o < 1024; o <<= 1) {
        int t = (tid >= o) ? s[tid - o] : 0;
        __syncthreads();
        s[tid] += t;
        __syncthreads();
    }
    if (tid < nb) bsum[tid] = s[tid] - v;
    if (tid == 0) eoff[N] = E;
}

__global__ void k_scanC(int* __restrict__ eoff, const int* __restrict__ bsum, int N) {
    int i = blockIdx.x * blockDim.x + threadIdx.x;
    if (i < N) eoff[i] += bsum[i >> 10];
}

// ---------------- CSR fill ----------------
__global__ void k_fill(const int* __restrict__ src, const int* __restrict__ dst,
                       const int* __restrict__ eoff, int* __restrict__ cursor,
                       int* __restrict__ esrc, int E) {
    int e = blockIdx.x * blockDim.x + threadIdx.x;
    if (e < E) {
        int d = dst[e];
        int pos = eoff[d] + atomicAdd(&cursor[d], 1);
        esrc[pos] = src[e];
    }
}

// ---------------- W prep: transpose + hi/lo bf16 split ----------------
// Wt1 [HID][2*IN_DIM]: row n = [hi(k=0..127) | lo(k=0..127)] of W1[:,n]
// Wt2 [OUTD][2*HID] likewise from W2.
__global__ void k_wprep(const float* __restrict__ W1, const float* __restrict__ W2,
                        unsigned short* __restrict__ Wt1, unsigned short* __restrict__ Wt2) {
    int t = blockIdx.x * 256 + threadIdx.x;
    if (t < IN_DIM * HID) {
        int k = t & (IN_DIM - 1), n = t >> 7;
        float wv = W1[(size_t)k * HID + n];
        unsigned short hi = f2bf(wv);
        Wt1[(size_t)n * (2 * IN_DIM) + k] = hi;
        Wt1[(size_t)n * (2 * IN_DIM) + IN_DIM + k] = f2bf(wv - bf2f(hi));
    }
    if (t < HID * OUTD) {
        int k = t & (HID - 1), n = t >> 8;
        float wv = W2[(size_t)k * OUTD + n];
        unsigned short hi = f2bf(wv);
        Wt2[(size_t)n * (2 * HID) + k] = hi;
        Wt2[(size_t)n * (2 * HID) + HID + k] = f2bf(wv - bf2f(hi));
    }
}

// ---------------- SPMM1: fp32 gather of h, output xcat = [hi|lo] bf16 [N][256] ----------------
// one wave per node; lanes = 32 float4-chunks x 2 edge-slots; 2x unrolled -> 4 gathers in flight
__global__ __launch_bounds__(256) void k_spmm1(const float* __restrict__ h,
                                               const int* __restrict__ eoff,
                                               const int* __restrict__ esrc,
                                               const float* __restrict__ ns,
                                               const float* __restrict__ nd,
                                               unsigned short* __restrict__ xcat, int N) {
    int wid = threadIdx.x >> 6;
    int v = blockIdx.x * 4 + wid;
    if (v >= N) return;
    int l = threadIdx.x & 63;
    int c = l & 31, el = l >> 5;
    int s0 = eoff[v], s1 = eoff[v + 1];

    float ax0 = 0.f, ay0 = 0.f, az0 = 0.f, aw0 = 0.f;
    float ax1 = 0.f, ay1 = 0.f, az1 = 0.f, aw1 = 0.f;
    int i = s0 + el;
    for (; i + 2 < s1; i += 4) {
        int sA = esrc[i], sB = esrc[i + 2];
        float nA = ns[sA], nB = ns[sB];
        float4 hA = *(const float4*)(h + (size_t)sA * IN_DIM + c * 4);
        float4 hB = *(const float4*)(h + (size_t)sB * IN_DIM + c * 4);
        ax0 += hA.x * nA; ay0 += hA.y * nA; az0 += hA.z * nA; aw0 += hA.w * nA;
        ax1 += hB.x * nB; ay1 += hB.y * nB; az1 += hB.z * nB; aw1 += hB.w * nB;
    }
    if (i < s1) {
        int sA = esrc[i];
        float nA = ns[sA];
        float4 hA = *(const float4*)(h + (size_t)sA * IN_DIM + c * 4);
        ax0 += hA.x * nA; ay0 += hA.y * nA; az0 += hA.z * nA; aw0 += hA.w * nA;
    }
    float ax = ax0 + ax1, ay = ay0 + ay1, az = az0 + az1, aw = aw0 + aw1;
    ax += __shfl_xor(ax, 32);
    ay += __shfl_xor(ay, 32);
    az += __shfl_xor(az, 32);
    aw += __shfl_xor(aw, 32);
    if (el == 0) {
        float ndv = nd[v];
        float f[4] = {ax * ndv, ay * ndv, az * ndv, aw * ndv};
        ushort4 hi4, lo4;
        unsigned short* hp = (unsigned short*)&hi4;
        unsigned short* lp = (unsigned short*)&lo4;
#pragma unroll
        for (int k = 0; k < 4; ++k) {
            unsigned short hb = f2bf(f[k]);
            hp[k] = hb;
            lp[k] = f2bf(f[k] - bf2f(hb));
        }
        *(ushort4*)(xcat + (size_t)v * 256 + c * 4) = hi4;
        *(ushort4*)(xcat + (size_t)v * 256 + 128 + c * 4) = lo4;
    }
}

// ---------------- MFMA GEMM: C = A(M x K,bf16cat) * Bt(N x K,bf16cat)^T ----------------
// BM=256, BN=64, BK=64; 4 waves, wave w owns rows [w*64, w*64+64) x all 64 cols.
// EPI 1: hid = relu(acc + b1)*clamp(p) -> hidcat [M][2*HID] hi/lo
// EPI 2: y = acc * ns[row]            -> ybf [M][OUTD] bf16
template <int EPI>
__global__ __launch_bounds__(256) void k_mgemm(const unsigned short* __restrict__ A,
                                               const unsigned short* __restrict__ Bt,
                                               const float* __restrict__ b1,
                                               const float* __restrict__ p,
                                               const float* __restrict__ ns,
                                               unsigned short* __restrict__ outHid,
                                               unsigned short* __restrict__ outY,
                                               int M, int K) {
    __shared__ unsigned short As[256 * 64];
    __shared__ unsigned short Bs[64 * 64];
    const int t = threadIdx.x;
    const int w = t >> 6;
    const int l = t & 63;
    const int row0 = blockIdx.x * 256;
    const int n0 = blockIdx.y * 64;

    f32x4 acc[4][4] = {};

    const int lr = l & 15;
    const int lk = (l >> 4) * 8;
    const int m0 = w * 64;

    for (int k0 = 0; k0 < K; k0 += 64) {
        // stage A tile: wave w stages 8KB (8 issues of 1KB)
#pragma unroll
        for (int q = 0; q < 8; ++q) {
            int r = w * 64 + q * 8 + (l >> 3);
            int cc = (l & 7) * 8;
            int gr = row0 + r;
            if (gr > M - 1) gr = M - 1;
            const unsigned short* gp = A + (size_t)gr * K + k0 + cc;
            unsigned short* lp = &As[w * 4096 + q * 512];
            __builtin_amdgcn_global_load_lds((const __attribute__((address_space(1))) void*)gp,
                                             (__attribute__((address_space(3))) void*)lp, 16, 0, 0);
        }
        // stage B tile: wave w stages 2KB (2 issues)
#pragma unroll
        for (int q = 0; q < 2; ++q) {
            int r = w * 16 + q * 8 + (l >> 3);
            int cc = (l & 7) * 8;
            const unsigned short* gp = Bt + (size_t)(n0 + r) * K + k0 + cc;
            unsigned short* lp = &Bs[w * 1024 + q * 512];
            __builtin_amdgcn_global_load_lds((const __attribute__((address_space(1))) void*)gp,
                                             (__attribute__((address_space(3))) void*)lp, 16, 0, 0);
        }
        __syncthreads();

#pragma unroll
        for (int kk = 0; kk < 2; ++kk) {
            bf16x8 a[4], b[4];
#pragma unroll
            for (int m = 0; m < 4; ++m)
                a[m] = *(const bf16x8*)&As[(m0 + m * 16 + lr) * 64 + kk * 32 + lk];
#pragma unroll
            for (int n = 0; n < 4; ++n)
                b[n] = *(const bf16x8*)&Bs[(n * 16 + lr) * 64 + kk * 32 + lk];
#pragma unroll
            for (int m = 0; m < 4; ++m)
#pragma unroll
                for (int n = 0; n < 4; ++n)
                    acc[m][n] = __builtin_amdgcn_mfma_f32_16x16x32_bf16(a[m], b[n], acc[m][n], 0, 0, 0);
        }
        __syncthreads();
    }

    // epilogue: C/D layout col = lane&15, row = (lane>>4)*4 + j
    const int lg = l >> 4;
#pragma unroll
    for (int n = 0; n < 4; ++n) {
        int col = n0 + n * 16 + lr;
        float bb = 0.f, pp = 1.f;
        if (EPI == 1) {
            bb = b1[col];
            float pr = p[col];
            pp = fminf(fmaxf(pr, 0.f), 1.f);
        }
#pragma unroll
        for (int m = 0; m < 4; ++m) {
            int rbase = row0 + w * 64 + m * 16 + lg * 4;
#pragma unroll
            for (int j = 0; j < 4; ++j) {
                int row = rbase + j;
                if (row < M) {
                    float v = acc[m][n][j];
                    if (EPI == 1) {
                        v = fmaxf(v + bb, 0.f) * pp;
                        unsigned short hb = f2bf(v);
                        outHid[(size_t)row * (2 * HID) + col] = hb;
                        outHid[(size_t)row * (2 * HID) + HID + col] = f2bf(v - bf2f(hb));
                    } else {
                        v *= ns[row];
                        outY[(size_t)row * OUTD + col] = f2bf(v);
                    }
                }
            }
        }
    }
}

// ---------------- SPMM2: bf16 gather of y, out fp32 ----------------
// one wave per node; lanes = 16 chunks(4 bf16) x 4 edge-slots; 2x unrolled -> 8 gathers in flight
__global__ __launch_bounds__(256) void k_spmm2(const unsigned short* __restrict__ ybf,
                                               const int* __restrict__ eoff,
                                               const int* __restrict__ esrc,
                                               const float* __restrict__ nd,
                                               const float* __restrict__ b2,
                                               float* __restrict__ out, int N) {
    int wid = threadIdx.x >> 6;
    int v = blockIdx.x * 4 + wid;
    if (v >= N) return;
    int l = threadIdx.x & 63;
    int c = l & 15, el = l >> 4;
    int s0 = eoff[v], s1 = eoff[v + 1];

    float ax0 = 0.f, ay0 = 0.f, az0 = 0.f, aw0 = 0.f;
    float ax1 = 0.f, ay1 = 0.f, az1 = 0.f, aw1 = 0.f;
    int i = s0 + el;
    for (; i + 4 < s1; i += 8) {
        int sA = esrc[i], sB = esrc[i + 4];
        ushort4 uA = *(const ushort4*)(ybf + (size_t)sA * OUTD + c * 4);
        ushort4 uB = *(const ushort4*)(ybf + (size_t)sB * OUTD + c * 4);
        ax0 += bf2f(uA.x); ay0 += bf2f(uA.y); az0 += bf2f(uA.z); aw0 += bf2f(uA.w);
        ax1 += bf2f(uB.x); ay1 += bf2f(uB.y); az1 += bf2f(uB.z); aw1 += bf2f(uB.w);
    }
    for (; i < s1; i += 4) {
        ushort4 u = *(const ushort4*)(ybf + (size_t)esrc[i] * OUTD + c * 4);
        ax0 += bf2f(u.x); ay0 += bf2f(u.y); az0 += bf2f(u.z); aw0 += bf2f(u.w);
    }
    float ax = ax0 + ax1, ay = ay0 + ay1, az = az0 + az1, aw = aw0 + aw1;
    ax += __shfl_xor(ax, 16); ax += __shfl_xor(ax, 32);
    ay += __shfl_xor(ay, 16); ay += __shfl_xor(ay, 32);
    az += __shfl_xor(az, 16); az += __shfl_xor(az, 32);
    aw += __shfl_xor(aw, 16); aw += __shfl_xor(aw, 32);
    if (l < 16) {
        float ndv = nd[v];
        float4 bb = *(const float4*)(b2 + c * 4);
        float4 o;
        o.x = ax * ndv + bb.x;
        o.y = ay * ndv + bb.y;
        o.z = az * ndv + bb.z;
        o.w = aw * ndv + bb.w;
        *(float4*)(out + (size_t)v * OUTD + c * 4) = o;
    }
}

extern "C" void kernel_launch(void* const* d_in, const int* in_sizes, int n_in,
                              void* d_out, int out_size, void* d_ws, size_t ws_size,
                              hipStream_t stream) {
    const float* h  = (const float*)d_in[0];
    const float* W1 = (const float*)d_in[1];
    const float* b1 = (const float*)d_in[2];
    const float* W2 = (const float*)d_in[3];
    const float* b2 = (const float*)d_in[4];
    const float* p  = (const float*)d_in[5];
    const int* src  = (const int*)d_in[6];
    const int* dst  = (const int*)d_in[7];

    const int N = in_sizes[0] / IN_DIM;
    const int E = in_sizes[6];
    float* out = (float*)d_out;

    char* ws = (char*)d_ws;
    size_t off = 0;
    auto alloc = [&](size_t bytes) -> void* {
        void* ptr = ws + off;
        off = (off + bytes + 255) & ~(size_t)255;
        return ptr;
    };
    int* cnt_src = (int*)alloc((size_t)N * 4);
    int* cnt_dst = (int*)alloc((size_t)N * 4);
    int* cursor  = (int*)alloc((size_t)N * 4);
    size_t zero_span = off;
    int* eoff   = (int*)alloc((size_t)(N + 1) * 4);
    int* bsum   = (int*)alloc(4096);
    int* esrc   = (int*)alloc((size_t)E * 4);
    float* ns   = (float*)alloc((size_t)N * 4);
    float* nd   = (float*)alloc((size_t)N * 4);
    unsigned short* xcat   = (unsigned short*)alloc((size_t)N * 256 * 2);        // 51.2 MB
    unsigned short* hidcat = (unsigned short*)alloc((size_t)N * (2 * HID) * 2);  // 102.4 MB
    unsigned short* Wt1    = (unsigned short*)alloc((size_t)HID * 256 * 2);
    unsigned short* Wt2    = (unsigned short*)alloc((size_t)OUTD * 512 * 2);
    unsigned short* ybf    = xcat;  // xcat dead after GEMM1; ybf (12.8MB) fits

    hipMemsetAsync(d_ws, 0, zero_span, stream);

    int tpb = 256;
    k_degrees<<<(E + tpb - 1) / tpb, tpb, 0, stream>>>(src, dst, cnt_src, cnt_dst, E);
    k_norms<<<(N + tpb - 1) / tpb, tpb, 0, stream>>>(cnt_src, cnt_dst, ns, nd, N);

    int nb = (N + 1023) / 1024;
    k_scanA<<<nb, 1024, 0, stream>>>(cnt_dst, eoff, bsum, N);
    k_scanB<<<1, 1024, 0, stream>>>(bsum, nb, eoff, N, E);
    k_scanC<<<(N + tpb - 1) / tpb, tpb, 0, stream>>>(eoff, bsum, N);
    k_fill<<<(E + tpb - 1) / tpb, tpb, 0, stream>>>(src, dst, eoff, cursor, esrc, E);

    k_wprep<<<(IN_DIM * HID + 255) / 256, 256, 0, stream>>>(W1, W2, Wt1, Wt2);

    k_spmm1<<<(N + 3) / 4, 256, 0, stream>>>(h, eoff, esrc, ns, nd, xcat, N);

    dim3 g1((N + 255) / 256, HID / 64);
    k_mgemm<1><<<g1, 256, 0, stream>>>(xcat, Wt1, b1, p, ns, hidcat, nullptr, N, 2 * IN_DIM);

    dim3 g2((N + 255) / 256, 1);
    k_mgemm<2><<<g2, 256, 0, stream>>>(hidcat, Wt2, nullptr, nullptr, ns, nullptr, ybf, N, 2 * HID);

    k_spmm2<<<(N + 3) / 4, 256, 0, stream>>>(ybf, eoff, esrc, nd, b2, out, N);
}

// Round 4
// 492.738 us; speedup vs baseline: 1.5170x; 1.2320x over previous
//
#include <hip/hip_runtime.h>

#define IN_DIM 128
#define HID 256
#define OUTD 64

typedef __attribute__((ext_vector_type(8))) short bf16x8;
typedef __attribute__((ext_vector_type(4))) float f32x4;
typedef __attribute__((ext_vector_type(8))) unsigned short ushort8v;

// ---- bf16 helpers (RNE) ----
__device__ __forceinline__ unsigned short f2bf(float x) {
    unsigned int u = __float_as_uint(x);
    unsigned int r = (u + 0x7fffu + ((u >> 16) & 1u)) >> 16;
    return (unsigned short)r;
}
__device__ __forceinline__ float bf2f(unsigned short b) {
    return __uint_as_float(((unsigned int)b) << 16);
}

// ---------------- degree / norm ----------------
__global__ void k_degrees(const int* __restrict__ src, const int* __restrict__ dst,
                          int* __restrict__ cs, int* __restrict__ cd, int E) {
    int e = blockIdx.x * blockDim.x + threadIdx.x;
    if (e < E) {
        atomicAdd(&cs[src[e]], 1);
        atomicAdd(&cd[dst[e]], 1);
    }
}

__global__ void k_norms(const int* __restrict__ cs, const int* __restrict__ cd,
                        float* __restrict__ ns, float* __restrict__ nd, int N) {
    int i = blockIdx.x * blockDim.x + threadIdx.x;
    if (i < N) {
        ns[i] = rsqrtf((float)max(cs[i], 1));
        nd[i] = rsqrtf((float)max(cd[i], 1));
    }
}

// ---------------- h pre-scale + bf16 convert: hb[v][d] = bf16(h[v][d]*ns[v]) ----------------
__global__ void k_hconv(const float* __restrict__ h, const float* __restrict__ ns,
                        unsigned short* __restrict__ hb, int total4) {
    int i = blockIdx.x * 256 + threadIdx.x;  // one float4 per thread
    if (i >= total4) return;
    int node = i >> 5;  // 32 float4 per row of 128
    float nsv = ns[node];
    float4 v = ((const float4*)h)[i];
    ushort4 o;
    o.x = f2bf(v.x * nsv);
    o.y = f2bf(v.y * nsv);
    o.z = f2bf(v.z * nsv);
    o.w = f2bf(v.w * nsv);
    ((ushort4*)hb)[i] = o;
}

// ---------------- scan ----------------
__global__ __launch_bounds__(1024) void k_scanA(const int* __restrict__ cnt,
                                                int* __restrict__ eoff,
                                                int* __restrict__ bsum, int N) {
    __shared__ int s[1024];
    int tid = threadIdx.x;
    int i = blockIdx.x * 1024 + tid;
    int v = (i < N) ? cnt[i] : 0;
    s[tid] = v;
    __syncthreads();
    for (int o = 1; o < 1024; o <<= 1) {
        int t = (tid >= o) ? s[tid - o] : 0;
        __syncthreads();
        s[tid] += t;
        __syncthreads();
    }
    if (i < N) eoff[i] = s[tid] - v;
    if (tid == 1023) bsum[blockIdx.x] = s[tid];
}

__global__ __launch_bounds__(1024) void k_scanB(int* __restrict__ bsum, int nb,
                                                int* __restrict__ eoff, int N, int E) {
    __shared__ int s[1024];
    int tid = threadIdx.x;
    int v = (tid < nb) ? bsum[tid] : 0;
    s[tid] = v;
    __syncthreads();
    for (int o = 1; o < 1024; o <<= 1) {
        int t = (tid >= o) ? s[tid - o] : 0;
        __syncthreads();
        s[tid] += t;
        __syncthreads();
    }
    if (tid < nb) bsum[tid] = s[tid] - v;
    if (tid == 0) eoff[N] = E;
}

__global__ void k_scanC(int* __restrict__ eoff, const int* __restrict__ bsum, int N) {
    int i = blockIdx.x * blockDim.x + threadIdx.x;
    if (i < N) eoff[i] += bsum[i >> 10];
}

// ---------------- CSR fill ----------------
__global__ void k_fill(const int* __restrict__ src, const int* __restrict__ dst,
                       const int* __restrict__ eoff, int* __restrict__ cursor,
                       int* __restrict__ esrc, int E) {
    int e = blockIdx.x * blockDim.x + threadIdx.x;
    if (e < E) {
        int d = dst[e];
        int pos = eoff[d] + atomicAdd(&cursor[d], 1);
        esrc[pos] = src[e];
    }
}

// ---------------- W prep: transpose + bf16 ----------------
// Wt1 [HID=256][IN_DIM=128], Wt2 [OUTD=64][HID=256], both N x K row-major
__global__ void k_wprep(const float* __restrict__ W1, const float* __restrict__ W2,
                        unsigned short* __restrict__ Wt1, unsigned short* __restrict__ Wt2) {
    int t = blockIdx.x * 256 + threadIdx.x;
    if (t < IN_DIM * HID) {
        int k = t & (IN_DIM - 1), n = t >> 7;
        Wt1[(size_t)n * IN_DIM + k] = f2bf(W1[(size_t)k * HID + n]);
    }
    if (t < HID * OUTD) {
        int k = t & (HID - 1), n = t >> 8;
        Wt2[(size_t)n * HID + k] = f2bf(W2[(size_t)k * OUTD + n]);
    }
}

// ---------------- SPMM1: bf16 gather of hb (pre-scaled), out xb bf16 [N][128] ----------------
// one wave per node; lanes = 16 chunks(8 bf16 = 16B) x 4 edge-slots; 2x unrolled -> 8 gathers in flight
__global__ __launch_bounds__(256) void k_spmm1(const unsigned short* __restrict__ hb,
                                               const int* __restrict__ eoff,
                                               const int* __restrict__ esrc,
                                               const float* __restrict__ nd,
                                               unsigned short* __restrict__ xb, int N) {
    int wid = threadIdx.x >> 6;
    int v = blockIdx.x * 4 + wid;
    if (v >= N) return;
    int l = threadIdx.x & 63;
    int c = l & 15, el = l >> 4;
    int s0 = eoff[v], s1 = eoff[v + 1];

    float a0[8] = {0.f, 0.f, 0.f, 0.f, 0.f, 0.f, 0.f, 0.f};
    float a1[8] = {0.f, 0.f, 0.f, 0.f, 0.f, 0.f, 0.f, 0.f};
    int i = s0 + el;
    for (; i + 4 < s1; i += 8) {
        int sA = esrc[i], sB = esrc[i + 4];
        ushort8v uA = *(const ushort8v*)(hb + (size_t)sA * IN_DIM + c * 8);
        ushort8v uB = *(const ushort8v*)(hb + (size_t)sB * IN_DIM + c * 8);
#pragma unroll
        for (int k = 0; k < 8; ++k) {
            a0[k] += bf2f((unsigned short)uA[k]);
            a1[k] += bf2f((unsigned short)uB[k]);
        }
    }
    for (; i < s1; i += 4) {
        int sA = esrc[i];
        ushort8v uA = *(const ushort8v*)(hb + (size_t)sA * IN_DIM + c * 8);
#pragma unroll
        for (int k = 0; k < 8; ++k) a0[k] += bf2f((unsigned short)uA[k]);
    }
    float s[8];
#pragma unroll
    for (int k = 0; k < 8; ++k) {
        float x = a0[k] + a1[k];
        x += __shfl_xor(x, 16);
        x += __shfl_xor(x, 32);
        s[k] = x;
    }
    if (el == 0) {
        float ndv = nd[v];
        uint4 o;
        unsigned int* op = (unsigned int*)&o;
#pragma unroll
        for (int k = 0; k < 4; ++k) {
            unsigned int lo = f2bf(s[2 * k] * ndv);
            unsigned int hi = f2bf(s[2 * k + 1] * ndv);
            op[k] = lo | (hi << 16);
        }
        *(uint4*)(xb + (size_t)v * IN_DIM + c * 8) = o;
    }
}

// ---------------- MFMA GEMM: C = A(M x K,bf16) * Bt(BN x K,bf16)^T ----------------
// EPI 1: BM=64, BN=256, K=128, waves split cols;  hid = bf16(relu(acc+b1)*clamp(p))
// EPI 2: BM=256, BN=64, K=256, waves split rows;  y = bf16(acc * ns[row])
template <int EPI>
__global__ __launch_bounds__(256) void k_mgemm(const unsigned short* __restrict__ A,
                                               const unsigned short* __restrict__ Bt,
                                               const float* __restrict__ b1,
                                               const float* __restrict__ p,
                                               const float* __restrict__ ns,
                                               unsigned short* __restrict__ outp,
                                               int M) {
    constexpr int BM = (EPI == 1) ? 64 : 256;
    constexpr int BN = (EPI == 1) ? 256 : 64;
    constexpr int K = (EPI == 1) ? 128 : 256;
    constexpr int OUT_LD = (EPI == 1) ? 256 : 64;
    __shared__ unsigned short As[BM * 64];
    __shared__ unsigned short Bs[BN * 64];
    const int t = threadIdx.x, w = t >> 6, l = t & 63;
    const int row0 = blockIdx.x * BM;
    const int wm0 = (EPI == 1) ? 0 : w * 64;
    const int wn0 = (EPI == 1) ? w * 64 : 0;
    const int lr = l & 15, lk = (l >> 4) * 8, lg = l >> 4;

    f32x4 acc[4][4] = {};

    for (int k0 = 0; k0 < K; k0 += 64) {
        // stage A tile [BM][64]
#pragma unroll
        for (int q = 0; q < BM / 32; ++q) {
            int chunk = w * (BM / 32) + q;
            int gr = row0 + chunk * 8 + (l >> 3);
            if (gr > M - 1) gr = M - 1;
            const unsigned short* gp = A + (size_t)gr * K + k0 + (l & 7) * 8;
            __builtin_amdgcn_global_load_lds((const __attribute__((address_space(1))) void*)gp,
                                             (__attribute__((address_space(3))) void*)&As[chunk * 512], 16, 0, 0);
        }
        // stage B tile [BN][64]
#pragma unroll
        for (int q = 0; q < BN / 32; ++q) {
            int chunk = w * (BN / 32) + q;
            int r = chunk * 8 + (l >> 3);
            const unsigned short* gp = Bt + (size_t)r * K + k0 + (l & 7) * 8;
            __builtin_amdgcn_global_load_lds((const __attribute__((address_space(1))) void*)gp,
                                             (__attribute__((address_space(3))) void*)&Bs[chunk * 512], 16, 0, 0);
        }
        __syncthreads();

#pragma unroll
        for (int kk = 0; kk < 2; ++kk) {
            bf16x8 a[4], b[4];
#pragma unroll
            for (int m = 0; m < 4; ++m)
                a[m] = *(const bf16x8*)&As[(wm0 + m * 16 + lr) * 64 + kk * 32 + lk];
#pragma unroll
            for (int n = 0; n < 4; ++n)
                b[n] = *(const bf16x8*)&Bs[(wn0 + n * 16 + lr) * 64 + kk * 32 + lk];
#pragma unroll
            for (int m = 0; m < 4; ++m)
#pragma unroll
                for (int n = 0; n < 4; ++n)
                    acc[m][n] = __builtin_amdgcn_mfma_f32_16x16x32_bf16(a[m], b[n], acc[m][n], 0, 0, 0);
        }
        __syncthreads();
    }

    // epilogue: C/D layout col = lane&15 (via lr), row = (lane>>4)*4 + j
#pragma unroll
    for (int n = 0; n < 4; ++n) {
        int col = wn0 + n * 16 + lr;
        float bb = 0.f, pp = 1.f;
        if (EPI == 1) {
            bb = b1[col];
            pp = fminf(fmaxf(p[col], 0.f), 1.f);
        }
#pragma unroll
        for (int m = 0; m < 4; ++m) {
#pragma unroll
            for (int j = 0; j < 4; ++j) {
                int row = row0 + wm0 + m * 16 + lg * 4 + j;
                if (row < M) {
                    float v = acc[m][n][j];
                    if (EPI == 1) {
                        v = fmaxf(v + bb, 0.f) * pp;
                    } else {
                        v *= ns[row];
                    }
                    outp[(size_t)row * OUT_LD + col] = f2bf(v);
                }
            }
        }
    }
}

// ---------------- SPMM2: bf16 gather of y, out fp32 ----------------
__global__ __launch_bounds__(256) void k_spmm2(const unsigned short* __restrict__ ybf,
                                               const int* __restrict__ eoff,
                                               const int* __restrict__ esrc,
                                               const float* __restrict__ nd,
                                               const float* __restrict__ b2,
                                               float* __restrict__ out, int N) {
    int wid = threadIdx.x >> 6;
    int v = blockIdx.x * 4 + wid;
    if (v >= N) return;
    int l = threadIdx.x & 63;
    int c = l & 15, el = l >> 4;
    int s0 = eoff[v], s1 = eoff[v + 1];

    float ax0 = 0.f, ay0 = 0.f, az0 = 0.f, aw0 = 0.f;
    float ax1 = 0.f, ay1 = 0.f, az1 = 0.f, aw1 = 0.f;
    int i = s0 + el;
    for (; i + 4 < s1; i += 8) {
        int sA = esrc[i], sB = esrc[i + 4];
        ushort4 uA = *(const ushort4*)(ybf + (size_t)sA * OUTD + c * 4);
        ushort4 uB = *(const ushort4*)(ybf + (size_t)sB * OUTD + c * 4);
        ax0 += bf2f(uA.x); ay0 += bf2f(uA.y); az0 += bf2f(uA.z); aw0 += bf2f(uA.w);
        ax1 += bf2f(uB.x); ay1 += bf2f(uB.y); az1 += bf2f(uB.z); aw1 += bf2f(uB.w);
    }
    for (; i < s1; i += 4) {
        ushort4 u = *(const ushort4*)(ybf + (size_t)esrc[i] * OUTD + c * 4);
        ax0 += bf2f(u.x); ay0 += bf2f(u.y); az0 += bf2f(u.z); aw0 += bf2f(u.w);
    }
    float ax = ax0 + ax1, ay = ay0 + ay1, az = az0 + az1, aw = aw0 + aw1;
    ax += __shfl_xor(ax, 16); ax += __shfl_xor(ax, 32);
    ay += __shfl_xor(ay, 16); ay += __shfl_xor(ay, 32);
    az += __shfl_xor(az, 16); az += __shfl_xor(az, 32);
    aw += __shfl_xor(aw, 16); aw += __shfl_xor(aw, 32);
    if (l < 16) {
        float ndv = nd[v];
        float4 bb = *(const float4*)(b2 + c * 4);
        float4 o;
        o.x = ax * ndv + bb.x;
        o.y = ay * ndv + bb.y;
        o.z = az * ndv + bb.z;
        o.w = aw * ndv + bb.w;
        *(float4*)(out + (size_t)v * OUTD + c * 4) = o;
    }
}

extern "C" void kernel_launch(void* const* d_in, const int* in_sizes, int n_in,
                              void* d_out, int out_size, void* d_ws, size_t ws_size,
                              hipStream_t stream) {
    const float* h  = (const float*)d_in[0];
    const float* W1 = (const float*)d_in[1];
    const float* b1 = (const float*)d_in[2];
    const float* W2 = (const float*)d_in[3];
    const float* b2 = (const float*)d_in[4];
    const float* p  = (const float*)d_in[5];
    const int* src  = (const int*)d_in[6];
    const int* dst  = (const int*)d_in[7];

    const int N = in_sizes[0] / IN_DIM;
    const int E = in_sizes[6];
    float* out = (float*)d_out;

    char* ws = (char*)d_ws;
    size_t off = 0;
    auto alloc = [&](size_t bytes) -> void* {
        void* ptr = ws + off;
        off = (off + bytes + 255) & ~(size_t)255;
        return ptr;
    };
    int* cnt_src = (int*)alloc((size_t)N * 4);
    int* cnt_dst = (int*)alloc((size_t)N * 4);
    int* cursor  = (int*)alloc((size_t)N * 4);
    size_t zero_span = off;
    int* eoff   = (int*)alloc((size_t)(N + 1) * 4);
    int* bsum   = (int*)alloc(4096);
    int* esrc   = (int*)alloc((size_t)E * 4);
    float* ns   = (float*)alloc((size_t)N * 4);
    float* nd   = (float*)alloc((size_t)N * 4);
    unsigned short* hb  = (unsigned short*)alloc((size_t)N * IN_DIM * 2);  // 25.6 MB
    unsigned short* xb  = (unsigned short*)alloc((size_t)N * IN_DIM * 2);  // 25.6 MB
    unsigned short* hid = (unsigned short*)alloc((size_t)N * HID * 2);     // 51.2 MB
    unsigned short* Wt1 = (unsigned short*)alloc((size_t)HID * IN_DIM * 2);
    unsigned short* Wt2 = (unsigned short*)alloc((size_t)OUTD * HID * 2);
    unsigned short* ybf = xb;  // xb dead after GEMM1; ybf (12.8 MB) fits

    hipMemsetAsync(d_ws, 0, zero_span, stream);

    int tpb = 256;
    k_degrees<<<(E + tpb - 1) / tpb, tpb, 0, stream>>>(src, dst, cnt_src, cnt_dst, E);
    k_norms<<<(N + tpb - 1) / tpb, tpb, 0, stream>>>(cnt_src, cnt_dst, ns, nd, N);

    int total4 = N * (IN_DIM / 4);
    k_hconv<<<(total4 + tpb - 1) / tpb, tpb, 0, stream>>>(h, ns, hb, total4);

    int nb = (N + 1023) / 1024;
    k_scanA<<<nb, 1024, 0, stream>>>(cnt_dst, eoff, bsum, N);
    k_scanB<<<1, 1024, 0, stream>>>(bsum, nb, eoff, N, E);
    k_scanC<<<(N + tpb - 1) / tpb, tpb, 0, stream>>>(eoff, bsum, N);
    k_fill<<<(E + tpb - 1) / tpb, tpb, 0, stream>>>(src, dst, eoff, cursor, esrc, E);

    k_wprep<<<(IN_DIM * HID + 255) / 256, 256, 0, stream>>>(W1, W2, Wt1, Wt2);

    k_spmm1<<<(N + 3) / 4, 256, 0, stream>>>(hb, eoff, esrc, nd, xb, N);

    k_mgemm<1><<<(N + 63) / 64, 256, 0, stream>>>(xb, Wt1, b1, p, nullptr, hid, N);

    k_mgemm<2><<<(N + 255) / 256, 256, 0, stream>>>(hid, Wt2, nullptr, nullptr, ns, ybf, N);

    k_spmm2<<<(N + 3) / 4, 256, 0, stream>>>(ybf, eoff, esrc, nd, b2, out, N);
}